// Round 4
// baseline (7557.943 us; speedup 1.0000x reference)
//
#include <hip/hip_runtime.h>

#define B 64
#define S 128
#define T 64
#define H 512
#define E 256
#define V 10000
#define H2 1024      // 2H
#define G4 2048      // 4H
#define KX 1536      // ctx(1024)+h(512) gate GEMM K
#define KP 1792      // E + H + 2H pre concat K
#define VP 10112     // padded V = 79*128
#define NROW 4096    // B*T

typedef unsigned short u16;
typedef __attribute__((ext_vector_type(8))) short bf16x8;
typedef __attribute__((ext_vector_type(4))) short bf16x4;
typedef __attribute__((ext_vector_type(4))) float floatx4;

__device__ inline float b2f(u16 h){
  union { unsigned int u; float f; } v; v.u = ((unsigned int)h) << 16; return v.f;
}
__device__ inline u16 f2b(float f){
  union { unsigned int u; float f; } v; v.f = f;
  unsigned int r = v.u + 0x7FFFu + ((v.u >> 16) & 1u);
  return (u16)(r >> 16);
}
__device__ inline float sigf(float x){ return 1.f/(1.f+__expf(-x)); }
__device__ inline float tanh_fast(float x){ float e=__expf(2.f*x); return 1.f - 2.f/(e+1.f); }

// ---- coherent (IF$-level) helpers: write-through stores, no cache invalidation ----
__device__ __forceinline__ void st_wt_u32(u16* p, unsigned v){
  asm volatile("global_store_dword %0, %1, off sc0 sc1 nt" :: "v"(p), "v"(v) : "memory");
}
__device__ __forceinline__ void st_wt_u16(u16* p, unsigned v){
  asm volatile("global_store_short %0, %1, off sc0 sc1 nt" :: "v"(p), "v"(v) : "memory");
}
__device__ __forceinline__ void st_wt_b128(u16* p, bf16x8 v){
  asm volatile("global_store_dwordx4 %0, %1, off sc0 sc1 nt" :: "v"(p), "v"(v) : "memory");
}

// ---------------- prep kernels ----------------
__global__ void k_cast(const float* __restrict__ src, u16* __restrict__ dst, int n){
  int i = blockIdx.x*256 + threadIdx.x;
  if (i < n) dst[i] = f2b(src[i]);
}
__global__ void k_tct(const float* __restrict__ src, u16* __restrict__ dst, int R, int C){
  __shared__ float tile[64][65];
  int c0 = blockIdx.x*64, r0 = blockIdx.y*64;
  int tid = threadIdx.x;
  #pragma unroll
  for (int i=0;i<16;i++){
    int flat = i*256 + tid;
    int rr = flat >> 6, cc = flat & 63;
    int c = c0 + cc;
    tile[rr][cc] = (c < C) ? src[(size_t)(r0+rr)*C + c] : 0.f;
  }
  __syncthreads();
  #pragma unroll
  for (int i=0;i<16;i++){
    int flat = i*256 + tid;
    int cc = flat >> 6, rr = flat & 63;
    dst[(size_t)(c0+cc)*R + r0 + rr] = f2b(tile[rr][cc]);
  }
}
__global__ void k_wch(const float* __restrict__ wih, const float* __restrict__ whh, u16* __restrict__ o){
  int i = blockIdx.x*256 + threadIdx.x;
  if (i < G4*KX){
    int gp = i / KX, k = i % KX;
    int j = gp >> 2, gate = gp & 3, g = gate*H + j;
    float v = (k < H2) ? wih[(size_t)g*(E+H2) + E + k] : whh[(size_t)g*H + (k - H2)];
    o[i] = f2b(v);
  }
}
__global__ void k_wihe(const float* __restrict__ wih, u16* __restrict__ o){
  int i = blockIdx.x*256 + threadIdx.x;
  if (i < G4*E){
    int gp = i / E, e = i % E;
    int j = gp >> 2, gate = gp & 3, g = gate*H + j;
    o[i] = f2b(wih[(size_t)g*(E+H2) + e]);
  }
}
__global__ void k_bias(const float* __restrict__ bi, const float* __restrict__ bh, float* __restrict__ o){
  int i = blockIdx.x*256 + threadIdx.x;
  if (i < G4){
    int j = i >> 2, gate = i & 3, g = gate*H + j;
    o[i] = bi[g] + bh[g];
  }
}
__global__ void k_emb(const int* __restrict__ trg, const float* __restrict__ emb, u16* __restrict__ catp){
  int i = blockIdx.x*256 + threadIdx.x;
  if (i < NROW*E){
    int row = i >> 8, e = i & 255;
    int tok = trg[row];
    catp[(size_t)row*KP + e] = f2b(emb[(size_t)tok*E + e]);
  }
}
__global__ void k_init(const int* __restrict__ unused, const float* __restrict__ h0, const float* __restrict__ c0,
                       u16* __restrict__ xgs, float* __restrict__ cb0){
  int i = blockIdx.x*256 + threadIdx.x;
  if (i < B*H){
    int b = i >> 9, j = i & 511;
    xgs[(size_t)b*KX + H2 + j] = f2b(h0[i]);   // slot 0 h-region
    cb0[i] = c0[i];
  }
}
__global__ void k_zero2(unsigned* bar){ bar[threadIdx.x] = 0u; }
__global__ void k_lse(const float* __restrict__ sep, float* __restrict__ lse){
  int r = blockIdx.x*256 + threadIdx.x;
  if (r < NROW){
    float s = 0.f;
    for (int i=0;i<79;i++) s += sep[(size_t)r*80 + i];
    lse[r] = logf(s);
  }
}
__global__ void k_fin(const float* __restrict__ hf, const float* __restrict__ cf, float* __restrict__ out){
  int i = blockIdx.x*256 + threadIdx.x;
  if (i < B*H){
    out[(size_t)B*V*T + i] = hf[i];
    out[(size_t)B*V*T + B*H + i] = cf[i];
  }
}

// ---------------- MFMA GEMM: C[row,col] = sum_k A[row,k]*BT[col,k] ----------------
template<int TN, int EPI>
__global__ __launch_bounds__(256) void gemm_bf16(
    const u16* __restrict__ A, int lda,
    const u16* __restrict__ BT, int ldb,
    int K,
    u16* outb, int ldc,
    float* sep,
    float* outp, const float* lse)
{
  constexpr int NSUB = TN/16;
  constexpr int NB = TN/64;
  __shared__ u16 sA[64*32];
  __shared__ u16 sB[TN*32];
  __shared__ float Cx[(EPI==3) ? 128*65 : 1];
  __shared__ float lseb[(EPI==3)?64:1];

  const int tid = threadIdx.x;
  const int lane = tid & 63;
  const int wv = tid >> 6;
  const int row0 = blockIdx.x * 64;
  const int n0 = blockIdx.y * TN;

  floatx4 acc[NSUB];
  #pragma unroll
  for (int s=0;s<NSUB;s++) acc[s] = (floatx4){0.f,0.f,0.f,0.f};

  const int ar = tid >> 2;
  const int ch = tid & 3;
  const int swz = (ar >> 1) & 3;
  const int px = ((lane & 15) >> 1) & 3;

  const u16* gA = A + (size_t)(row0+ar)*lda + ch*8;
  bf16x8 pa = *(const bf16x8*)gA;
  bf16x8 pb[NB];
  #pragma unroll
  for (int i=0;i<NB;i++) pb[i] = *(const bf16x8*)(BT + (size_t)(n0+i*64+ar)*ldb + ch*8);

  for (int k0 = 0; k0 < K; k0 += 32){
    __syncthreads();
    *(bf16x8*)&sA[ar*32 + ((ch ^ swz)*8)] = pa;
    #pragma unroll
    for (int i=0;i<NB;i++)
      *(bf16x8*)&sB[(i*64+ar)*32 + ((ch ^ swz)*8)] = pb[i];
    __syncthreads();
    if (k0 + 32 < K){
      pa = *(const bf16x8*)(gA + k0 + 32);
      #pragma unroll
      for (int i=0;i<NB;i++) pb[i] = *(const bf16x8*)(BT + (size_t)(n0+i*64+ar)*ldb + k0+32 + ch*8);
    }
    bf16x8 af = *(const bf16x8*)&sA[(16*wv + (lane&15))*32 + (((lane>>4) ^ px)*8)];
    #pragma unroll
    for (int s=0;s<NSUB;s++){
      bf16x8 bfv = *(const bf16x8*)&sB[(16*s + (lane&15))*32 + (((lane>>4) ^ px)*8)];
      acc[s] = __builtin_amdgcn_mfma_f32_16x16x32_bf16(af, bfv, acc[s], 0, 0, 0);
    }
  }

  if constexpr (EPI == 0){
    #pragma unroll
    for (int s=0;s<NSUB;s++)
      #pragma unroll
      for (int r=0;r<4;r++){
        int row = row0 + 16*wv + ((lane>>4)<<2) + r;
        int col = n0 + 16*s + (lane&15);
        outb[(size_t)row*ldc + col] = f2b(acc[s][r]);
      }
  }
  if constexpr (EPI == 2){
    float sr[4] = {0.f,0.f,0.f,0.f};
    #pragma unroll
    for (int s=0;s<NSUB;s++){
      int col = n0 + 16*s + (lane&15);
      if (col < V){
        #pragma unroll
        for (int r=0;r<4;r++) sr[r] += __expf(acc[s][r]);
      }
    }
    #pragma unroll
    for (int r=0;r<4;r++){
      float v = sr[r];
      v += __shfl_xor(v,1); v += __shfl_xor(v,2); v += __shfl_xor(v,4); v += __shfl_xor(v,8);
      sr[r] = v;
    }
    if ((lane&15)==0){
      #pragma unroll
      for (int r=0;r<4;r++){
        int row = row0 + 16*wv + ((lane>>4)<<2) + r;
        sep[(size_t)row*80 + blockIdx.y] = sr[r];
      }
    }
  }
  if constexpr (EPI == 3){
    #pragma unroll
    for (int s=0;s<NSUB;s++)
      #pragma unroll
      for (int r=0;r<4;r++){
        int rl = 16*wv + ((lane>>4)<<2) + r;
        int cl = 16*s + (lane&15);
        Cx[cl*65 + rl] = acc[s][r];
      }
    if (tid < 64) lseb[tid] = lse[row0 + tid];
    __syncthreads();
    int b = blockIdx.x;
    for (int idx = tid; idx < TN*16; idx += 256){
      int vl = idx >> 4, q4 = idx & 15;
      int v = n0 + vl;
      if (v < V){
        floatx4 o;
        o[0] = Cx[vl*65 + q4*4+0] - lseb[q4*4+0];
        o[1] = Cx[vl*65 + q4*4+1] - lseb[q4*4+1];
        o[2] = Cx[vl*65 + q4*4+2] - lseb[q4*4+2];
        o[3] = Cx[vl*65 + q4*4+3] - lseb[q4*4+3];
        *(floatx4*)&outp[((size_t)b*V + v)*T + q4*4] = o;
      }
    }
  }
}

// ---------------- fence-free grid barrier (relaxed IF$-coherent atomics) ----------------
__device__ __forceinline__ void gbar(unsigned* bar, int slot){
  // drain this wave's write-through stores (visible at IF$ once vmcnt==0)
  asm volatile("s_waitcnt vmcnt(0)" ::: "memory");
  __syncthreads();   // all waves of this block drained
  if (threadIdx.x == 0){
    unsigned* cnt = bar + slot*64;
    unsigned* gen = bar + slot*64 + 16;
    unsigned g, old, one = 1u, z = 0u;
    // read generation BEFORE arriving
    asm volatile("global_load_dword %0, %1, off sc0 sc1\ns_waitcnt vmcnt(0)"
                 : "=v"(g) : "v"(gen) : "memory");
    asm volatile("global_atomic_add %0, %1, %2, off sc0 sc1\ns_waitcnt vmcnt(0)"
                 : "=v"(old) : "v"(cnt), "v"(one) : "memory");
    if (old == 63u){
      asm volatile("global_store_dword %0, %1, off sc0 sc1\ns_waitcnt vmcnt(0)"
                   :: "v"(cnt), "v"(z) : "memory");
      asm volatile("global_atomic_add %0, %1, off sc1" :: "v"(gen), "v"(one) : "memory");
    } else {
      unsigned gg = g;
      do {
        asm volatile("s_sleep 1" :::);
        asm volatile("global_load_dword %0, %1, off sc0 sc1\ns_waitcnt vmcnt(0)"
                     : "=v"(gg) : "v"(gen) : "memory");
      } while (gg == g);
    }
  }
  __syncthreads();
}

// ---------------- persistent recurrence megakernel: 64 blocks x 512 threads ----------------
// Fresh-slot communication: xgs has T+1 slots of [B][KX]; qbuf has T slots of [B][H] bf16.
// Cross-block writes are write-through (sc0 sc1); reads are normal (first-touch per address).
__global__ __launch_bounds__(512) void decoder_loop(
    u16* __restrict__ xgs, float* __restrict__ cbuf, float* __restrict__ hfin,
    const u16* __restrict__ pk, const u16* __restrict__ encb,
    const float* __restrict__ we, const int* __restrict__ lens,
    const u16* __restrict__ wqb, u16* __restrict__ cph,
    const u16* __restrict__ wch, const u16* __restrict__ gemb,
    const float* __restrict__ bias, u16* __restrict__ qbuf, unsigned* __restrict__ bar)
{
  __shared__ u16 sA[64*128];
  __shared__ u16 sB[32*128];
  __shared__ float Cx[64*33];
  __shared__ float qw[512], wel[512], ep[512];
  __shared__ float ev[S], al[S];
  __shared__ float smax, sinv;

  const int tid = threadIdx.x, lane = tid & 63;
  const int blk = blockIdx.x;
  const int b = blk;
  const int n0 = blk*32;
  const int wv = tid >> 6, rw = wv & 3, cw = wv >> 2;
  const int lenb = lens[b];
  wel[tid] = we[tid];

  // phase Q mapping: block covers rows qr*8..qr*8+7, cols qc*64..qc*64+63
  const int qr = blk >> 3, qc = blk & 7;
  const int qrr = tid >> 6;            // row within group (= wave)
  const int j8 = (lane >> 3);          // col octet
  const int ks = lane & 7;             // K-slice (64 wide)

  // gates staging indices
  const int ra = tid >> 3, ca = tid & 7;
  const int rb = tid >> 4, cb = tid & 15;
  const int rowa = 16*rw + (lane & 15);
  const int rowb = 16*cw + (lane & 15);

  for (int t=0; t<T; t++){
    const u16* xgt = xgs + (size_t)t*B*KX;       // slot t: [ctx | h] for step t
    u16* xgn = xgs + (size_t)(t+1)*B*KX;         // slot t+1: h written here
    const float* cin_ = cbuf + (size_t)(t&1)*B*H;
    float* cout_ = cbuf + (size_t)((t+1)&1)*B*H;
    u16* qb = qbuf + (size_t)t*B*H;

    // ===== phase Q: q = h_t @ Wquery, distributed 8x8 blocks, 8-way K-split =====
    {
      int bq = qr*8 + qrr;
      const u16* hrow = xgt + (size_t)bq*KX + H2 + ks*64;
      bf16x8 h8[8];
      #pragma unroll
      for (int i=0;i<8;i++) h8[i] = *(const bf16x8*)(hrow + i*8);
      const u16* wp = wqb + (size_t)(ks*64)*H + qc*64 + j8*8;
      float a8[8] = {0.f,0.f,0.f,0.f,0.f,0.f,0.f,0.f};
      #pragma unroll 2
      for (int kk8=0; kk8<8; kk8++){
        float hf[8];
        #pragma unroll
        for (int m=0;m<8;m++) hf[m] = b2f((u16)h8[kk8][m]);
        #pragma unroll
        for (int m=0;m<8;m++){
          bf16x8 w8 = *(const bf16x8*)(wp + (size_t)(kk8*8+m)*H);
          #pragma unroll
          for (int i=0;i<8;i++) a8[i] += hf[m]*b2f((u16)w8[i]);
        }
      }
      #pragma unroll
      for (int m=1; m<8; m<<=1){
        #pragma unroll
        for (int i=0;i<8;i++) a8[i] += __shfl_xor(a8[i], m);
      }
      if (ks == 0){
        bf16x8 qpack;
        #pragma unroll
        for (int i=0;i<8;i++) qpack[i] = (short)f2b(a8[i]);
        st_wt_b128(qb + (size_t)bq*H + qc*64 + j8*8, qpack);
      }
    }
    gbar(bar, 0);

    // ===== phase A: attention for batch b =====
    qw[tid] = b2f(qb[(size_t)b*H + tid]);
    __syncthreads();
    {
      int s = tid >> 2, part = tid & 3;
      const u16* pr = pk + (size_t)(b*S + s)*H;
      float a0 = 0.f;
      #pragma unroll 4
      for (int m=0;m<16;m++){
        int k0 = part*8 + m*32;
        bf16x8 p8 = *(const bf16x8*)(pr + k0);
        #pragma unroll
        for (int i=0;i<8;i++){
          float x = qw[k0+i] + b2f((u16)p8[i]);
          a0 += tanh_fast(x) * wel[k0+i];
        }
      }
      ep[tid] = a0;
    }
    __syncthreads();
    if (tid < S){
      float e = ep[tid*4] + ep[tid*4+1] + ep[tid*4+2] + ep[tid*4+3];
      ev[tid] = (tid < lenb) ? e : -1e30f;
    }
    __syncthreads();
    if (tid < 64){
      float m = fmaxf(ev[tid], ev[tid+64]);
      #pragma unroll
      for (int o=32;o>=1;o>>=1) m = fmaxf(m, __shfl_xor(m,o));
      if (tid==0) smax = m;
    }
    __syncthreads();
    if (tid < S) al[tid] = __expf(ev[tid]-smax);
    __syncthreads();
    if (tid < 64){
      float s2 = al[tid] + al[tid+64];
      #pragma unroll
      for (int o=32;o>=1;o>>=1) s2 += __shfl_xor(s2,o);
      if (tid==0) sinv = 1.f/s2;
    }
    __syncthreads();
    {
      float c0=0.f, c1=0.f;
      int d = tid*2;
      const u16* er = encb + (size_t)(b*S)*H2 + d;
      for (int ss=0; ss<S; ss++){
        unsigned int u = *(const unsigned int*)(er + (size_t)ss*H2);
        float a = al[ss];
        c0 += a * b2f((u16)(u & 0xFFFFu));
        c1 += a * b2f((u16)(u >> 16));
      }
      c0 *= sinv; c1 *= sinv;
      unsigned pack = ((unsigned)f2b(c1) << 16) | (unsigned)f2b(c0);
      st_wt_u32((u16*)(xgt + (size_t)b*KX + d), pack);   // ctx into slot t (read by phase B)
      size_t cr = (size_t)(b*T + t)*KP + E + H + d;
      *(unsigned*)&cph[cr] = pack;                        // normal store, read post-kernel
    }
    gbar(bar, 1);

    // ===== phase B: gates GEMM [64 x 32] over K=1536 + LSTM pointwise =====
    const int pb_ = tid >> 3, pj = tid & 7;
    bf16x4 g4 = *(const bf16x4*)(gemb + (size_t)(pb_*T + t)*G4 + n0 + pj*4);
    floatx4 bias4 = *(const floatx4*)(bias + n0 + pj*4);
    float cold = cin_[pb_*H + (n0>>2) + pj];

    bf16x8 a0 = *(const bf16x8*)(xgt + (size_t)ra*KX + ca*8);
    bf16x8 a1 = *(const bf16x8*)(xgt + (size_t)ra*KX + (ca+8)*8);
    bf16x8 b0 = *(const bf16x8*)(wch + (size_t)(n0+rb)*KX + cb*8);
    floatx4 acc = (floatx4){0.f,0.f,0.f,0.f};

    for (int kk=0; kk<12; kk++){
      __syncthreads();
      *(bf16x8*)&sA[ra*128 + ((ca ^ (ra&7))*8)] = a0;
      *(bf16x8*)&sA[ra*128 + (((ca+8) ^ (ra&7))*8)] = a1;
      *(bf16x8*)&sB[rb*128 + ((cb ^ (rb&7))*8)] = b0;
      __syncthreads();
      if (kk < 11){
        int ko = (kk+1)*128;
        a0 = *(const bf16x8*)(xgt + (size_t)ra*KX + ko + ca*8);
        a1 = *(const bf16x8*)(xgt + (size_t)ra*KX + ko + (ca+8)*8);
        b0 = *(const bf16x8*)(wch + (size_t)(n0+rb)*KX + ko + cb*8);
      }
      #pragma unroll
      for (int s=0;s<4;s++){
        int q = s*4 + (lane>>4);
        bf16x8 af = *(const bf16x8*)&sA[rowa*128 + ((q ^ (rowa&7))*8)];
        bf16x8 bfv = *(const bf16x8*)&sB[rowb*128 + ((q ^ (rowb&7))*8)];
        acc = __builtin_amdgcn_mfma_f32_16x16x32_bf16(af, bfv, acc, 0, 0, 0);
      }
    }
    {
      int r0 = 16*rw + ((lane>>4)<<2);
      int col = 16*cw + (lane&15);
      #pragma unroll
      for (int r=0;r<4;r++) Cx[(r0+r)*33 + col] = acc[r];
    }
    __syncthreads();
    {
      float gi = Cx[pb_*33 + pj*4+0] + b2f((u16)g4[0]) + bias4[0];
      float gf = Cx[pb_*33 + pj*4+1] + b2f((u16)g4[1]) + bias4[1];
      float gg = Cx[pb_*33 + pj*4+2] + b2f((u16)g4[2]) + bias4[2];
      float go = Cx[pb_*33 + pj*4+3] + b2f((u16)g4[3]) + bias4[3];
      float cn = sigf(gf)*cold + sigf(gi)*tanhf(gg);
      float hn = sigf(go)*tanhf(cn);
      int j = (n0>>2) + pj;
      cout_[pb_*H + j] = cn;
      if (t == T-1) hfin[pb_*H + j] = hn;
      unsigned hb = (unsigned)f2b(hn);
      st_wt_u16(xgn + (size_t)pb_*KX + H2 + j, hb);       // h into slot t+1
      cph[(size_t)(pb_*T + t)*KP + E + j] = (u16)hb;       // normal store
    }
    gbar(bar, 2);
  }
}

static inline int cdiv(int a, int b){ return (a + b - 1) / b; }

extern "C" void kernel_launch(void* const* d_in, const int* in_sizes, int n_in,
                              void* d_out, int out_size, void* d_ws, size_t ws_size,
                              hipStream_t stream)
{
  (void)in_sizes; (void)n_in; (void)out_size; (void)ws_size;
  const int*   trg  = (const int*)d_in[0];
  const float* enc  = (const float*)d_in[1];
  const int*   lens = (const int*)d_in[2];
  const float* h0   = (const float*)d_in[3];
  const float* c0   = (const float*)d_in[4];
  const float* embt = (const float*)d_in[5];
  const float* wkey = (const float*)d_in[6];
  const float* wqry = (const float*)d_in[7];
  const float* we   = (const float*)d_in[8];
  const float* wih  = (const float*)d_in[9];
  const float* whh  = (const float*)d_in[10];
  const float* bi   = (const float*)d_in[11];
  const float* bh   = (const float*)d_in[12];
  const float* wpre = (const float*)d_in[13];
  const float* wgen = (const float*)d_in[14];
  float* out = (float*)d_out;

  char* p = (char*)d_ws;
  auto carve = [&](size_t bytes)->char*{ char* r = p; p += (bytes + 255) & ~(size_t)255; return r; };
  u16*   encb  = (u16*)  carve((size_t)B*S*H2*2);
  u16*   pkb   = (u16*)  carve((size_t)B*S*H*2);
  u16*   catp  = (u16*)  carve((size_t)NROW*KP*2);
  u16*   gembb = (u16*)  carve((size_t)NROW*G4*2);
  u16*   preb  = (u16*)  carve((size_t)NROW*H*2);   // post-loop only; overlaid by qbuf in-loop
  u16*   wgt   = (u16*)  carve((size_t)VP*H*2);
  u16*   wch   = (u16*)  carve((size_t)G4*KX*2);
  u16*   wihe  = (u16*)  carve((size_t)G4*E*2);
  u16*   wkeyT = (u16*)  carve((size_t)H*H2*2);
  u16*   wqb   = (u16*)  carve((size_t)H*H*2);
  u16*   wpreT = (u16*)  carve((size_t)H*KP*2);
  u16*   xgs   = (u16*)  carve((size_t)(T+1)*B*KX*2);  // 65 fresh slots
  float* cbuf  = (float*)carve((size_t)2*B*H*4);
  float* hfin  = (float*)carve((size_t)B*H*4);
  float* biasp = (float*)carve((size_t)G4*4);
  float* sep   = (float*)carve((size_t)NROW*80*4);
  float* lse   = (float*)carve((size_t)NROW*4);
  unsigned* bar = (unsigned*)carve(1024);
  u16* qbuf = preb;   // T*B*H*2 == NROW*H*2 bytes; preb used only after loop ends

  // ---- prep ----
  k_cast<<<cdiv(B*S*H2,256),256,0,stream>>>(enc, encb, B*S*H2);
  k_cast<<<cdiv(H*H,256),256,0,stream>>>(wqry, wqb, H*H);
  k_tct<<<dim3(H/64, H2/64),256,0,stream>>>(wkey, wkeyT, H2, H);
  k_tct<<<dim3(H/64, KP/64),256,0,stream>>>(wpre, wpreT, KP, H);
  k_tct<<<dim3(VP/64, H/64),256,0,stream>>>(wgen, wgt, H, V);
  k_wch<<<cdiv(G4*KX,256),256,0,stream>>>(wih, whh, wch);
  k_wihe<<<cdiv(G4*E,256),256,0,stream>>>(wih, wihe);
  k_bias<<<cdiv(G4,256),256,0,stream>>>(bi, bh, biasp);
  k_emb<<<cdiv(NROW*E,256),256,0,stream>>>(trg, embt, catp);
  k_init<<<cdiv(B*H,256),256,0,stream>>>(trg, h0, c0, xgs, cbuf);
  k_zero2<<<1,256,0,stream>>>(bar);

  // proj_key = enc @ Wkey  -> pk bf16 [B*S][H]
  gemm_bf16<64,0><<<dim3(B*S/64, H/64),256,0,stream>>>(
      encb, H2, wkeyT, H2, H2, pkb, H, nullptr, nullptr, nullptr);
  // Gemb = emb @ W_ih[:, :E].T (permuted cols) -> bf16 [NROW][G4]
  gemm_bf16<64,0><<<dim3(NROW/64, G4/64),256,0,stream>>>(
      catp, KP, wihe, E, E, gembb, G4, nullptr, nullptr, nullptr);

  // ---- recurrence: persistent kernel, 3 fence-free grid barriers per step ----
  decoder_loop<<<64,512,0,stream>>>(xgs, cbuf, hfin, pkb, encb, we, lens,
                                    wqb, catp, wch, gembb, biasp, qbuf, bar);

  // pre = cat_pre @ Wpre -> bf16 [NROW][H]
  gemm_bf16<64,0><<<dim3(NROW/64, H/64),256,0,stream>>>(
      catp, KP, wpreT, KP, KP, preb, H, nullptr, nullptr, nullptr);

  // generator pass 1: sum-exp partials
  gemm_bf16<128,2><<<dim3(NROW/64, VP/128),256,0,stream>>>(
      preb, H, wgt, H, H, nullptr, 0, sep, nullptr, nullptr);
  k_lse<<<cdiv(NROW,256),256,0,stream>>>(sep, lse);
  // generator pass 2: write out[b][v][t] = logit - lse
  gemm_bf16<128,3><<<dim3(NROW/64, VP/128),256,0,stream>>>(
      preb, H, wgt, H, H, nullptr, 0, nullptr, out, lse);

  k_fin<<<cdiv(B*H,256),256,0,stream>>>(hfin, cbuf, out);
}

// Round 5
// 3205.503 us; speedup vs baseline: 2.3578x; 2.3578x over previous
//
#include <hip/hip_runtime.h>

#define B 64
#define S 128
#define T 64
#define H 512
#define E 256
#define V 10000
#define H2 1024      // 2H
#define G4 2048      // 4H
#define KX 1536      // ctx(1024)+h(512) gate GEMM K
#define KP 1792      // E + H + 2H pre concat K
#define VP 10112     // padded V = 79*128
#define NROW 4096    // B*T

typedef unsigned short u16;
typedef __attribute__((ext_vector_type(8))) short bf16x8;
typedef __attribute__((ext_vector_type(4))) short bf16x4;
typedef __attribute__((ext_vector_type(4))) float floatx4;

__device__ inline float b2f(u16 h){
  union { unsigned int u; float f; } v; v.u = ((unsigned int)h) << 16; return v.f;
}
__device__ inline u16 f2b(float f){
  union { unsigned int u; float f; } v; v.f = f;
  unsigned int r = v.u + 0x7FFFu + ((v.u >> 16) & 1u);
  return (u16)(r >> 16);
}
__device__ inline float sigf(float x){ return 1.f/(1.f+__expf(-x)); }
__device__ inline float tanh_fast(float x){ float e=__expf(2.f*x); return 1.f - 2.f/(e+1.f); }

// ---------------- prep kernels ----------------
__global__ void k_cast(const float* __restrict__ src, u16* __restrict__ dst, int n){
  int i = blockIdx.x*256 + threadIdx.x;
  if (i < n) dst[i] = f2b(src[i]);
}
// tiled transpose-cast: src fp32 [R][C] -> dst bf16 [Cpad][R], rows c>=C zeroed
__global__ void k_tct(const float* __restrict__ src, u16* __restrict__ dst, int R, int C){
  __shared__ float tile[64][65];
  int c0 = blockIdx.x*64, r0 = blockIdx.y*64;
  int tid = threadIdx.x;
  #pragma unroll
  for (int i=0;i<16;i++){
    int flat = i*256 + tid;
    int rr = flat >> 6, cc = flat & 63;
    int c = c0 + cc;
    tile[rr][cc] = (c < C) ? src[(size_t)(r0+rr)*C + c] : 0.f;
  }
  __syncthreads();
  #pragma unroll
  for (int i=0;i<16;i++){
    int flat = i*256 + tid;
    int cc = flat >> 6, rr = flat & 63;
    dst[(size_t)(c0+cc)*R + r0 + rr] = f2b(tile[rr][cc]);
  }
}
__global__ void k_wch(const float* __restrict__ wih, const float* __restrict__ whh, u16* __restrict__ o){
  int i = blockIdx.x*256 + threadIdx.x;
  if (i < G4*KX){
    int gp = i / KX, k = i % KX;
    int j = gp >> 2, gate = gp & 3, g = gate*H + j;
    float v = (k < H2) ? wih[(size_t)g*(E+H2) + E + k] : whh[(size_t)g*H + (k - H2)];
    o[i] = f2b(v);
  }
}
__global__ void k_wihe(const float* __restrict__ wih, u16* __restrict__ o){
  int i = blockIdx.x*256 + threadIdx.x;
  if (i < G4*E){
    int gp = i / E, e = i % E;
    int j = gp >> 2, gate = gp & 3, g = gate*H + j;
    o[i] = f2b(wih[(size_t)g*(E+H2) + e]);
  }
}
__global__ void k_bias(const float* __restrict__ bi, const float* __restrict__ bh, float* __restrict__ o){
  int i = blockIdx.x*256 + threadIdx.x;
  if (i < G4){
    int j = i >> 2, gate = i & 3, g = gate*H + j;
    o[i] = bi[g] + bh[g];
  }
}
__global__ void k_emb(const int* __restrict__ trg, const float* __restrict__ emb, u16* __restrict__ catp){
  int i = blockIdx.x*256 + threadIdx.x;
  if (i < NROW*E){
    int row = i >> 8, e = i & 255;
    int tok = trg[row];
    catp[(size_t)row*KP + e] = f2b(emb[(size_t)tok*E + e]);
  }
}
__global__ void k_init(const float* __restrict__ h0, const float* __restrict__ c0,
                       u16* __restrict__ xg0, float* __restrict__ cb0){
  int i = blockIdx.x*256 + threadIdx.x;
  if (i < B*H){
    int b = i >> 9, j = i & 511;
    xg0[b*KX + H2 + j] = f2b(h0[i]);
    cb0[i] = c0[i];
  }
}
__global__ void k_lse(const float* __restrict__ sep, float* __restrict__ lse){
  int r = blockIdx.x*256 + threadIdx.x;
  if (r < NROW){
    float s = 0.f;
    for (int i=0;i<79;i++) s += sep[(size_t)r*80 + i];
    lse[r] = logf(s);
  }
}
__global__ void k_fin(const float* __restrict__ hf, const float* __restrict__ cf, float* __restrict__ out){
  int i = blockIdx.x*256 + threadIdx.x;
  if (i < B*H){
    out[(size_t)B*V*T + i] = hf[i];
    out[(size_t)B*V*T + B*H + i] = cf[i];
  }
}

// ---------------- MFMA GEMM: C[row,col] = sum_k A[row,k]*BT[col,k] ----------------
template<int TN, int EPI>
__global__ __launch_bounds__(256) void gemm_bf16(
    const u16* __restrict__ A, int lda,
    const u16* __restrict__ BT, int ldb,
    int K,
    u16* outb, int ldc,
    float* sep,
    float* outp, const float* lse)
{
  constexpr int NSUB = TN/16;
  constexpr int NB = TN/64;
  __shared__ u16 sA[64*32];
  __shared__ u16 sB[TN*32];
  __shared__ float Cx[(EPI==3) ? 128*65 : 1];
  __shared__ float lseb[(EPI==3)?64:1];

  const int tid = threadIdx.x;
  const int lane = tid & 63;
  const int wv = tid >> 6;
  const int row0 = blockIdx.x * 64;
  const int n0 = blockIdx.y * TN;

  floatx4 acc[NSUB];
  #pragma unroll
  for (int s=0;s<NSUB;s++) acc[s] = (floatx4){0.f,0.f,0.f,0.f};

  const int ar = tid >> 2;
  const int ch = tid & 3;
  const int swz = (ar >> 1) & 3;
  const int px = ((lane & 15) >> 1) & 3;

  const u16* gA = A + (size_t)(row0+ar)*lda + ch*8;
  bf16x8 pa = *(const bf16x8*)gA;
  bf16x8 pb[NB];
  #pragma unroll
  for (int i=0;i<NB;i++) pb[i] = *(const bf16x8*)(BT + (size_t)(n0+i*64+ar)*ldb + ch*8);

  for (int k0 = 0; k0 < K; k0 += 32){
    __syncthreads();
    *(bf16x8*)&sA[ar*32 + ((ch ^ swz)*8)] = pa;
    #pragma unroll
    for (int i=0;i<NB;i++)
      *(bf16x8*)&sB[(i*64+ar)*32 + ((ch ^ swz)*8)] = pb[i];
    __syncthreads();
    if (k0 + 32 < K){
      pa = *(const bf16x8*)(gA + k0 + 32);
      #pragma unroll
      for (int i=0;i<NB;i++) pb[i] = *(const bf16x8*)(BT + (size_t)(n0+i*64+ar)*ldb + k0+32 + ch*8);
    }
    bf16x8 af = *(const bf16x8*)&sA[(16*wv + (lane&15))*32 + (((lane>>4) ^ px)*8)];
    #pragma unroll
    for (int s=0;s<NSUB;s++){
      bf16x8 bfv = *(const bf16x8*)&sB[(16*s + (lane&15))*32 + (((lane>>4) ^ px)*8)];
      acc[s] = __builtin_amdgcn_mfma_f32_16x16x32_bf16(af, bfv, acc[s], 0, 0, 0);
    }
  }

  if constexpr (EPI == 0){
    #pragma unroll
    for (int s=0;s<NSUB;s++)
      #pragma unroll
      for (int r=0;r<4;r++){
        int row = row0 + 16*wv + ((lane>>4)<<2) + r;
        int col = n0 + 16*s + (lane&15);
        outb[(size_t)row*ldc + col] = f2b(acc[s][r]);
      }
  }
  if constexpr (EPI == 2){
    float sr[4] = {0.f,0.f,0.f,0.f};
    #pragma unroll
    for (int s=0;s<NSUB;s++){
      int col = n0 + 16*s + (lane&15);
      if (col < V){
        #pragma unroll
        for (int r=0;r<4;r++) sr[r] += __expf(acc[s][r]);
      }
    }
    #pragma unroll
    for (int r=0;r<4;r++){
      float v = sr[r];
      v += __shfl_xor(v,1); v += __shfl_xor(v,2); v += __shfl_xor(v,4); v += __shfl_xor(v,8);
      sr[r] = v;
    }
    if ((lane&15)==0){
      #pragma unroll
      for (int r=0;r<4;r++){
        int row = row0 + 16*wv + ((lane>>4)<<2) + r;
        sep[(size_t)row*80 + blockIdx.y] = sr[r];
      }
    }
  }
  if constexpr (EPI == 3){
    #pragma unroll
    for (int s=0;s<NSUB;s++)
      #pragma unroll
      for (int r=0;r<4;r++){
        int rl = 16*wv + ((lane>>4)<<2) + r;
        int cl = 16*s + (lane&15);
        Cx[cl*65 + rl] = acc[s][r];
      }
    if (tid < 64) lseb[tid] = lse[row0 + tid];
    __syncthreads();
    int b = blockIdx.x;
    for (int idx = tid; idx < TN*16; idx += 256){
      int vl = idx >> 4, q4 = idx & 15;
      int v = n0 + vl;
      if (v < V){
        floatx4 o;
        o[0] = Cx[vl*65 + q4*4+0] - lseb[q4*4+0];
        o[1] = Cx[vl*65 + q4*4+1] - lseb[q4*4+1];
        o[2] = Cx[vl*65 + q4*4+2] - lseb[q4*4+2];
        o[3] = Cx[vl*65 + q4*4+3] - lseb[q4*4+3];
        *(floatx4*)&outp[((size_t)b*V + v)*T + q4*4] = o;
      }
    }
  }
}

// ---------------- per-step attention (one block per batch element) ----------------
__global__ __launch_bounds__(512) void attn_step(
    u16* __restrict__ xg,          // read h at [b][H2..], write ctx at [b][0..H2)
    const u16* __restrict__ pk,    // [B*S][H] bf16
    const u16* __restrict__ encb,  // [B*S][H2] bf16
    const float* __restrict__ we,
    const int* __restrict__ lens,
    const u16* __restrict__ wqT,   // [H][H]: wqT[j][k] = Wquery[k][j]
    u16* __restrict__ cph,
    int t)
{
  __shared__ u16 hsb[H];
  __shared__ float qw[H], wel[H];
  __shared__ float ep[512];
  __shared__ float ev[S], al[S];
  __shared__ float smax, sinv;
  const int tid = threadIdx.x;
  const int lane = tid & 63;
  const int wv = tid >> 6;
  const int b = blockIdx.x;

  hsb[tid] = xg[b*KX + H2 + tid];   // h is already bf16
  wel[tid] = we[tid];
  __syncthreads();

  // q = h @ Wquery via MFMA: A = broadcast h (all 16 rows), B = wqT rows (cols of q)
  // wave w covers q columns [w*64, w*64+64)
  {
    floatx4 accq[4];
    #pragma unroll
    for (int s=0;s<4;s++) accq[s] = (floatx4){0.f,0.f,0.f,0.f};
    const int kc = (lane>>4)*8;
    #pragma unroll 4
    for (int ks=0; ks<16; ks++){
      bf16x8 af = *(const bf16x8*)&hsb[ks*32 + kc];
      #pragma unroll
      for (int s=0;s<4;s++){
        const u16* bp = wqT + (size_t)(wv*64 + s*16 + (lane&15))*H + ks*32 + kc;
        accq[s] = __builtin_amdgcn_mfma_f32_16x16x32_bf16(af, *(const bf16x8*)bp, accq[s], 0, 0, 0);
      }
    }
    if (lane < 16){
      #pragma unroll
      for (int s=0;s<4;s++) qw[wv*64 + s*16 + lane] = accq[s][0];
    }
  }
  __syncthreads();

  // energies: 4 threads per s
  {
    int s = tid >> 2, part = tid & 3;
    const u16* pr = pk + (size_t)(b*S + s)*H;
    float a0 = 0.f;
    #pragma unroll 4
    for (int m=0;m<16;m++){
      int k0 = part*8 + m*32;
      bf16x8 p8 = *(const bf16x8*)(pr + k0);
      #pragma unroll
      for (int i=0;i<8;i++){
        float x = qw[k0+i] + b2f((u16)p8[i]);
        a0 += tanh_fast(x) * wel[k0+i];
      }
    }
    ep[tid] = a0;
  }
  __syncthreads();
  if (tid < S){
    float e = ep[tid*4] + ep[tid*4+1] + ep[tid*4+2] + ep[tid*4+3];
    ev[tid] = (tid < lens[b]) ? e : -1e30f;
  }
  __syncthreads();
  if (tid < 64){
    float m = fmaxf(ev[tid], ev[tid+64]);
    #pragma unroll
    for (int o=32;o>=1;o>>=1) m = fmaxf(m, __shfl_xor(m,o));
    if (tid==0) smax = m;
  }
  __syncthreads();
  if (tid < S) al[tid] = __expf(ev[tid]-smax);
  __syncthreads();
  if (tid < 64){
    float s2 = al[tid] + al[tid+64];
    #pragma unroll
    for (int o=32;o>=1;o>>=1) s2 += __shfl_xor(s2,o);
    if (tid==0) sinv = 1.f/s2;
  }
  __syncthreads();

  // ctx: 2 dims per thread (fp32 accumulate)
  {
    float c0=0.f, c1=0.f;
    int d = tid*2;
    const u16* er = encb + (size_t)(b*S)*H2 + d;
    for (int ss=0; ss<S; ss++){
      unsigned int u = *(const unsigned int*)(er + (size_t)ss*H2);
      float a = al[ss];
      c0 += a * b2f((u16)(u & 0xFFFFu));
      c1 += a * b2f((u16)(u >> 16));
    }
    c0 *= sinv; c1 *= sinv;
    u16 h0b = f2b(c0), h1b = f2b(c1);
    xg[b*KX + d] = h0b; xg[b*KX + d + 1] = h1b;
    size_t cr = (size_t)(b*T + t)*KP + E + H + d;
    cph[cr] = h0b; cph[cr+1] = h1b;
  }
}

// ---------------- per-step gates GEMM + LSTM pointwise ----------------
// 128 blocks x 256 threads (4 waves). Block covers 16 gate-cols, all 64 batch rows, K=1536.
__global__ __launch_bounds__(256) void step_gemm(
    const u16* __restrict__ xgc,   // A [64][KX]
    const u16* __restrict__ wch,   // BT [2048][KX]
    const u16* __restrict__ gemb, const float* __restrict__ bias,
    const float* __restrict__ cin, float* __restrict__ cout,
    float* __restrict__ hfin, u16* __restrict__ xgn, u16* __restrict__ cph, int t)
{
  __shared__ u16 sA[64*128];
  __shared__ u16 sB[16*128];
  __shared__ float Cx[64*17];
  const int tid = threadIdx.x, lane = tid & 63, wv = tid >> 2 >> 4;  // wv = tid>>6
  const int w4 = tid >> 6;
  const int n0 = blockIdx.x * 16;
  (void)wv;

  floatx4 acc = (floatx4){0.f,0.f,0.f,0.f};

  // staging: A thread t -> row t>>2, chunks (t&3)*4..+3 (64B contiguous)
  const int ra = tid >> 2, ca0 = (tid & 3) * 4;
  // B: thread t -> row t>>4, chunk t&15
  const int rb = tid >> 4, cb = tid & 15;

  bf16x8 pa[4]; bf16x8 pbv;
  #pragma unroll
  for (int i=0;i<4;i++) pa[i] = *(const bf16x8*)(xgc + (size_t)ra*KX + (ca0+i)*8);
  pbv = *(const bf16x8*)(wch + (size_t)(n0+rb)*KX + cb*8);

  const int rowa = 16*w4 + (lane & 15);
  const int rowb = lane & 15;

  for (int kk=0; kk<12; kk++){
    __syncthreads();
    #pragma unroll
    for (int i=0;i<4;i++)
      *(bf16x8*)&sA[ra*128 + (((ca0+i) ^ (ra&7))*8)] = pa[i];
    *(bf16x8*)&sB[rb*128 + ((cb ^ (rb&7))*8)] = pbv;
    __syncthreads();
    if (kk < 11){
      int ko = (kk+1)*128;
      #pragma unroll
      for (int i=0;i<4;i++) pa[i] = *(const bf16x8*)(xgc + (size_t)ra*KX + ko + (ca0+i)*8);
      pbv = *(const bf16x8*)(wch + (size_t)(n0+rb)*KX + ko + cb*8);
    }
    #pragma unroll
    for (int ks=0; ks<4; ks++){
      int q = ks*4 + (lane>>4);
      bf16x8 af = *(const bf16x8*)&sA[rowa*128 + ((q ^ (rowa&7))*8)];
      bf16x8 bfv = *(const bf16x8*)&sB[rowb*128 + ((q ^ (rowb&7))*8)];
      acc = __builtin_amdgcn_mfma_f32_16x16x32_bf16(af, bfv, acc, 0, 0, 0);
    }
  }
  {
    int r0 = 16*w4 + ((lane>>4)<<2);
    int col = lane & 15;
    #pragma unroll
    for (int r=0;r<4;r++) Cx[(r0+r)*17 + col] = acc[r];
  }
  __syncthreads();

  // LSTM pointwise: thread -> (b = tid>>2, jl = tid&3)
  {
    const int pb_ = tid >> 2, jl = tid & 3;
    const int gp = n0 + jl*4;
    const int j = (n0 >> 2) + jl;
    bf16x4 g4 = *(const bf16x4*)(gemb + (size_t)(pb_*T + t)*G4 + gp);
    floatx4 bias4 = *(const floatx4*)(bias + gp);
    float cold = cin[pb_*H + j];
    float gi = Cx[pb_*17 + jl*4+0] + b2f((u16)g4[0]) + bias4[0];
    float gf = Cx[pb_*17 + jl*4+1] + b2f((u16)g4[1]) + bias4[1];
    float gg = Cx[pb_*17 + jl*4+2] + b2f((u16)g4[2]) + bias4[2];
    float go = Cx[pb_*17 + jl*4+3] + b2f((u16)g4[3]) + bias4[3];
    float cn = sigf(gf)*cold + sigf(gi)*tanhf(gg);
    float hn = sigf(go)*tanhf(cn);
    cout[pb_*H + j] = cn;
    if (t == T-1) hfin[pb_*H + j] = hn;
    u16 hb = f2b(hn);
    xgn[pb_*KX + H2 + j] = hb;
    cph[(size_t)(pb_*T + t)*KP + E + j] = hb;
  }
}

static inline int cdiv(int a, int b){ return (a + b - 1) / b; }

extern "C" void kernel_launch(void* const* d_in, const int* in_sizes, int n_in,
                              void* d_out, int out_size, void* d_ws, size_t ws_size,
                              hipStream_t stream)
{
  (void)in_sizes; (void)n_in; (void)out_size; (void)ws_size;
  const int*   trg  = (const int*)d_in[0];
  const float* enc  = (const float*)d_in[1];
  const int*   lens = (const int*)d_in[2];
  const float* h0   = (const float*)d_in[3];
  const float* c0   = (const float*)d_in[4];
  const float* embt = (const float*)d_in[5];
  const float* wkey = (const float*)d_in[6];
  const float* wqry = (const float*)d_in[7];
  const float* we   = (const float*)d_in[8];
  const float* wih  = (const float*)d_in[9];
  const float* whh  = (const float*)d_in[10];
  const float* bi   = (const float*)d_in[11];
  const float* bh   = (const float*)d_in[12];
  const float* wpre = (const float*)d_in[13];
  const float* wgen = (const float*)d_in[14];
  float* out = (float*)d_out;

  char* p = (char*)d_ws;
  auto carve = [&](size_t bytes)->char*{ char* r = p; p += (bytes + 255) & ~(size_t)255; return r; };
  u16*   encb  = (u16*)  carve((size_t)B*S*H2*2);
  u16*   pkb   = (u16*)  carve((size_t)B*S*H*2);
  u16*   catp  = (u16*)  carve((size_t)NROW*KP*2);
  u16*   gembb = (u16*)  carve((size_t)NROW*G4*2);
  u16*   preb  = (u16*)  carve((size_t)NROW*H*2);
  u16*   wgt   = (u16*)  carve((size_t)VP*H*2);
  u16*   wch   = (u16*)  carve((size_t)G4*KX*2);
  u16*   wihe  = (u16*)  carve((size_t)G4*E*2);
  u16*   wkeyT = (u16*)  carve((size_t)H*H2*2);
  u16*   wqT   = (u16*)  carve((size_t)H*H*2);
  u16*   wpreT = (u16*)  carve((size_t)H*KP*2);
  u16*   xg    = (u16*)  carve((size_t)2*B*KX*2);
  float* cbuf  = (float*)carve((size_t)2*B*H*4);
  float* hfin  = (float*)carve((size_t)B*H*4);
  float* biasp = (float*)carve((size_t)G4*4);
  float* sep   = (float*)carve((size_t)NROW*80*4);
  float* lse   = (float*)carve((size_t)NROW*4);

  // ---- prep ----
  k_cast<<<cdiv(B*S*H2,256),256,0,stream>>>(enc, encb, B*S*H2);
  k_tct<<<dim3(H/64, H/64),256,0,stream>>>(wqry, wqT, H, H);         // -> [H][H] (j,k)
  k_tct<<<dim3(H/64, H2/64),256,0,stream>>>(wkey, wkeyT, H2, H);     // -> [H][H2]
  k_tct<<<dim3(H/64, KP/64),256,0,stream>>>(wpre, wpreT, KP, H);     // -> [H][KP]
  k_tct<<<dim3(VP/64, H/64),256,0,stream>>>(wgen, wgt, H, V);        // -> [VP][H]
  k_wch<<<cdiv(G4*KX,256),256,0,stream>>>(wih, whh, wch);
  k_wihe<<<cdiv(G4*E,256),256,0,stream>>>(wih, wihe);
  k_bias<<<cdiv(G4,256),256,0,stream>>>(bi, bh, biasp);
  k_emb<<<cdiv(NROW*E,256),256,0,stream>>>(trg, embt, catp);
  k_init<<<cdiv(B*H,256),256,0,stream>>>(h0, c0, xg, cbuf);

  // proj_key = enc @ Wkey  -> pk bf16 [B*S][H]
  gemm_bf16<64,0><<<dim3(B*S/64, H/64),256,0,stream>>>(
      encb, H2, wkeyT, H2, H2, pkb, H, nullptr, nullptr, nullptr);
  // Gemb = emb @ W_ih[:, :E].T (permuted cols) -> bf16 [NROW][G4]
  gemm_bf16<64,0><<<dim3(NROW/64, G4/64),256,0,stream>>>(
      catp, KP, wihe, E, E, gembb, G4, nullptr, nullptr, nullptr);

  // ---- recurrence ----
  for (int t=0; t<T; t++){
    u16* xgc = xg + (size_t)(t&1)*B*KX;
    u16* xgn = xg + (size_t)((t+1)&1)*B*KX;
    float* cin_  = cbuf + (size_t)(t&1)*B*H;
    float* cout_ = cbuf + (size_t)((t+1)&1)*B*H;
    attn_step<<<B,512,0,stream>>>(xgc, pkb, encb, we, lens, wqT, catp, t);
    step_gemm<<<G4/16,256,0,stream>>>(xgc, wch, gembb, biasp, cin_, cout_, hfin, xgn, catp, t);
  }

  // pre = cat_pre @ Wpre -> bf16 [NROW][H]
  gemm_bf16<64,0><<<dim3(NROW/64, H/64),256,0,stream>>>(
      catp, KP, wpreT, KP, KP, preb, H, nullptr, nullptr, nullptr);

  // generator pass 1: sum-exp partials
  gemm_bf16<128,2><<<dim3(NROW/64, VP/128),256,0,stream>>>(
      preb, H, wgt, H, H, nullptr, 0, sep, nullptr, nullptr);
  k_lse<<<cdiv(NROW,256),256,0,stream>>>(sep, lse);
  // generator pass 2: write out[b][v][t] = logit - lse
  gemm_bf16<128,3><<<dim3(NROW/64, VP/128),256,0,stream>>>(
      preb, H, wgt, H, H, nullptr, 0, nullptr, out, lse);

  k_fin<<<cdiv(B*H,256),256,0,stream>>>(hfin, cbuf, out);
}